// Round 7
// baseline (96.368 us; speedup 1.0000x reference)
//
#include <hip/hip_runtime.h>

// out[b][s][d] = W[d][s] + bias[d]  for b in [0,4), s in [0,4096), d in [0,1024)
// ALL f32. W is [1024, 8192] row-major (row stride ML=8192 floats). x unused:
// one_hot(arange(S)) @ W.T + b is a row-gather = transpose of W[:, :S] + bias.
//
// Write-BW-bound transpose. R6: 64d x 32s tiles, grid 2048 (8 blocks/CU vs 4)
// to overlap one block's store phase against another's load phase and halve
// per-block barrier-drain exposure. Traffic unchanged: 16 MiB read + 64 MiB
// write @ ~6.4 TB/s (rate harness fills achieve) => 13 us kernel floor.
// NOTE: bench dur_us (~95) includes ~63-70 us of harness poison/restore ops.
//
// LDS: tile[s][d] 32x64 f32 (8 KB), XOR swizzle at float4-group granularity:
//   element (s,d) at word s*64 + ((((d>>2)&7) ^ ((s>>2)&7)) | ((d>>2)&8))*4 + (d&3)
// scatter-store banks: 4*((dr>>2)^sv) + (dr&3) -> 32 banks x 2 lanes (2-way = free);
// b128 reads: start banks uniform over all 8 clusters (structural minimum).

#define S_DIM  4096
#define D_DIM  1024
#define ML     8192
#define BATCH  4
#define TILE_S 32
#define TILE_D 64

__global__ __launch_bounds__(256) void pos_emb_kernel(const float* __restrict__ W,
                                                      const float* __restrict__ bias,
                                                      float* __restrict__ out) {
    __shared__ float tile[TILE_S * TILE_D];  // 8 KB, group-swizzled

    const int tid = threadIdx.x;
    const int s0  = (int)(blockIdx.x & 127) * TILE_S;  // 128 s-tiles
    const int d0  = (int)(blockIdx.x >> 7) * TILE_D;   // 16 d-tiles

    // ---- Load phase: coalesced along s, swizzled scatter into LDS ----
    // sv = float4 chunk along s (0..7), dr = d row (0..31), 2 passes over d
    const int sv = tid & 7;
    const int dr = tid >> 3;
    #pragma unroll
    for (int p = 0; p < 2; ++p) {
        const int d = dr + p * 32;
        const float4 v = *reinterpret_cast<const float4*>(
            &W[(size_t)(d0 + d) * ML + (size_t)s0 + sv * 4]);
        // logical group g = d>>2 = (dr>>2) + 8p ; s>>2 == sv for all 4 elems
        const int G   = ((dr >> 2) ^ sv) + 8 * p;  // swizzled group (low 3 bits XORed)
        const int off = dr & 3;
        const float vv[4] = {v.x, v.y, v.z, v.w};
        #pragma unroll
        for (int j = 0; j < 4; ++j) {
            const int srow = sv * 4 + j;
            tile[srow * TILE_D + G * 4 + off] = vv[j];
        }
    }

    // ---- Bias for write-phase d-slice (independent of LDS, overlaps latency) ----
    const int dv = tid & 15;   // float4 group along d (0..15)
    const int sr = tid >> 4;   // s row (0..15), 2 passes over s
    const float4 bvec = *reinterpret_cast<const float4*>(&bias[d0 + dv * 4]);

    __syncthreads();

    // ---- Write phase: swizzled b128 LDS read, coalesced float4 stores x4 batches ----
    #pragma unroll
    for (int p = 0; p < 2; ++p) {
        const int s = sr + p * 16;
        const int G = ((dv & 7) ^ (s >> 2)) | (dv & 8);  // un-swizzle logical group dv
        float4 v = *reinterpret_cast<const float4*>(&tile[s * TILE_D + G * 4]);
        v.x += bvec.x; v.y += bvec.y; v.z += bvec.z; v.w += bvec.w;
        const size_t o = (size_t)(s0 + s) * D_DIM + (size_t)d0 + dv * 4;
        #pragma unroll
        for (int b = 0; b < BATCH; ++b) {
            *reinterpret_cast<float4*>(&out[(size_t)b * S_DIM * D_DIM + o]) = v;
        }
    }
}

extern "C" void kernel_launch(void* const* d_in, const int* in_sizes, int n_in,
                              void* d_out, int out_size, void* d_ws, size_t ws_size,
                              hipStream_t stream) {
    // inputs: [0] x (unused, f32), [1] W [1024*8192] f32, [2] b [1024] f32
    const float* W = (const float*)d_in[1];
    const float* b = (const float*)d_in[2];
    float* out     = (float*)d_out;

    const int grid = (S_DIM / TILE_S) * (D_DIM / TILE_D);  // 128 * 16 = 2048
    pos_emb_kernel<<<dim3(grid), dim3(256), 0, stream>>>(W, b, out);
}